// Round 7
// baseline (4704.766 us; speedup 1.0000x reference)
//
#include <hip/hip_runtime.h>
#include <math.h>

constexpr int SVEC = 576;    // N_CH * 64
constexpr int INF  = 2304;   // 4 * SVEC
constexpr int HID  = 256;
constexpr int OUTF = 1152;   // 2 * SVEC
constexpr int TS   = 20;
constexpr int MR   = 16;     // samples per step-block
constexpr int CSL  = 24;     // float4-slots per K-chunk (of 144)
constexpr int NCHK = 6;      // 144 / CSL chunks
constexpr int CK   = 96;     // K elems per cc-range per chunk (CSL*4)
constexpr int AROW = 392;    // 4*CK + 8 pad (ushorts)

// ---------- helpers ----------------------------------------------------------
__device__ __forceinline__ ushort f2bf(float f) {    // RNE f32->bf16
    union { float f; unsigned u; } a; a.f = f;
    unsigned r = a.u + 0x7fff + ((a.u >> 16) & 1);
    return (ushort)(r >> 16);
}
__device__ __forceinline__ float bf2f(ushort b) {
    union { unsigned u; float f; } a; a.u = ((unsigned)b) << 16;
    return a.f;
}

typedef short  s16x8 __attribute__((ext_vector_type(8)));
typedef float  f32x4 __attribute__((ext_vector_type(4)));

// ---------- init: S = [x|p|y|z] all = [noisy, 0...] --------------------------
__global__ __launch_bounds__(256) void k_init(float4* __restrict__ S4,
                                              const float4* __restrict__ noisy4,
                                              int total4) {
    int i = blockIdx.x * 256 + threadIdx.x;
    if (i >= total4) return;
    int sample = i / 576;
    int j = i - sample * 576;
    int jc = j % 144;
    float4 v = make_float4(0.f, 0.f, 0.f, 0.f);
    if (jc < 16) v = noisy4[sample * 16 + jc];
    S4[i] = v;
}

__global__ __launch_bounds__(128) void k_zero(float* __restrict__ p, int n) {
    int i = blockIdx.x * 128 + threadIdx.x;
    if (i < n) p[i] = 0.f;
}

// ---------- weight transpose + bf16 convert: Wt[n*K+k] = W[k*N+n] ------------
__global__ __launch_bounds__(256) void k_wt(const float* __restrict__ W,
                                            ushort* __restrict__ Wt,
                                            int K, int N, int total) {
    int i = blockIdx.x * 256 + threadIdx.x;
    if (i >= total) return;
    int n = i / K, k = i - n * K;
    Wt[i] = f2bf(W[(size_t)k * N + n]);
}

// ---------- fully fused step: FBS + MLP(3 layers) + reductions ---------------
// One block = 16 samples. Phases:
//  1. alpha from prev step's buckets
//  2. 6x (FBS K-chunk -> LDS A-buf | MFMA GEMM1 chunk), double-buffered
//  3. GEMM1 epilogue -> H1 (LDS, reuses A space); r/d atomics
//  4. GEMM2 (K=256, B from L2) -> H2 (LDS)
//  5. GEMM3 (K=256, 3 passes) -> uv (bf16, global) + Q atomics
__global__ __launch_bounds__(256, 4) void k_step(float4* __restrict__ S4,
                                                 ushort* __restrict__ uv,
                                                 const float* __restrict__ redprev,
                                                 float* __restrict__ redcur,
                                                 const ushort* __restrict__ Wt1,
                                                 const float* __restrict__ b1,
                                                 const ushort* __restrict__ Wt2,
                                                 const float* __restrict__ b2,
                                                 const ushort* __restrict__ Wt3,
                                                 const float* __restrict__ b3,
                                                 float an) {
    __shared__ ushort A[2][MR][AROW];                 // 25088 B
    __shared__ float s_alpha, sr[4], sd[4], sq[4];
    ushort* Hbase = &A[0][0][0];
    // H1: rows 0..15 stride 264 at offset 0; H2 at offset 16*264 (disjoint)
    const int tid = threadIdx.x;
    const int m0 = blockIdx.x * MR;
    const int lane = tid & 63, wave = tid >> 6;
    const int lm = lane & 15, quad = lane >> 4;
    const int wn = wave * 64;
    const ushort4* uvb = (const ushort4*)uv;

    // ---- phase 1: alpha (slot 0 zeros -> alpha 0)
    if (tid < 64) {
        float v = (tid < 32) ? redprev[32 + tid] : redprev[64 + (tid - 32)];
        #pragma unroll
        for (int off = 16; off > 0; off >>= 1) v += __shfl_down(v, off);
        float Q = __shfl(v, 32);
        if (tid == 0) {
            float Qs = 1.5f * Q + 1e-12f;
            float b  = 0.99f * fmaxf(v, 0.f);
            s_alpha = sqrtf(fminf(b / Qs, 1.f));
        }
    }
    __syncthreads();
    const float al = s_alpha;

    float r = 0.f, d = 0.f;
    f32x4 acc[4];
    #pragma unroll
    for (int j = 0; j < 4; ++j) acc[j] = (f32x4){0.f, 0.f, 0.f, 0.f};

    auto fbs_chunk = [&](int ch, int buf) {
        for (int t = tid; t < MR * CSL; t += 256) {
            int smp = t / CSL, jj = t - smp * CSL;
            int j = ch * CSL + jj;
            size_t base = (size_t)(m0 + smp) * 576 + j;
            float4 x4 = S4[base], p4 = S4[base + 144];
            float4 y4 = S4[base + 288], z4 = S4[base + 432];
            size_t ub = (size_t)(m0 + smp) * 288 + j;
            ushort4 ubv = uvb[ub], vbv = uvb[ub + 144];
            float4 xn4, pr4, yy4, zz4;
            ushort4 bxn, bpr, byy, bzz;
            const float* X = (const float*)&x4;  const float* P = (const float*)&p4;
            const float* Y0 = (const float*)&y4; const float* Z0 = (const float*)&z4;
            const ushort* UB = (const ushort*)&ubv; const ushort* VB = (const ushort*)&vbv;
            float* XN = (float*)&xn4; float* PR = (float*)&pr4;
            float* YY = (float*)&yy4; float* ZZ = (float*)&zz4;
            ushort* BX = (ushort*)&bxn; ushort* BP = (ushort*)&bpr;
            ushort* BY = (ushort*)&byy; ushort* BZ = (ushort*)&bzz;
            #pragma unroll
            for (int c = 0; c < 4; ++c) {
                float x = X[c], p = P[c], y0 = Y0[c], z0 = Z0[c];
                float u = al * bf2f(UB[c]), v = al * bf2f(VB[c]);
                float y  = x + an * (y0 - x) + u;
                float dz = an * (z0 - p);
                float z  = x + an * (p - x) + dz + u + v;
                float zm = z - y;
                float tt = fabsf(zm) - 0.1f;
                float pr = (tt > 0.f) ? copysignf(tt, zm) : 0.f;
                float xn = x + (pr - z) + dz;
                XN[c] = xn; PR[c] = pr; YY[c] = y; ZZ[c] = z;
                BX[c] = f2bf(xn); BP[c] = f2bf(pr); BY[c] = f2bf(y); BZ[c] = f2bf(z);
                float e1 = pr - y; r += e1 * e1;
                float e2 = xn - z; d += e2 * e2;
            }
            S4[base] = xn4; S4[base + 144] = pr4;
            S4[base + 288] = yy4; S4[base + 432] = zz4;
            ushort* Ar = &A[buf][smp][0];
            *(ushort4*)&Ar[         jj * 4] = bxn;
            *(ushort4*)&Ar[CK     + jj * 4] = bpr;
            *(ushort4*)&Ar[2 * CK + jj * 4] = byy;
            *(ushort4*)&Ar[3 * CK + jj * 4] = bzz;
        }
    };
    auto mfma_chunk = [&](int ch, int buf) {
        #pragma unroll
        for (int cc = 0; cc < 4; ++cc) {
            const ushort* Wb = Wt1 + (size_t)(wn + lm) * INF + cc * 576 + ch * CK;
            #pragma unroll
            for (int k0 = 0; k0 < CK; k0 += 32) {
                s16x8 af  = *(const s16x8*)&A[buf][lm][cc * CK + k0 + quad * 8];
                s16x8 bf0 = *(const s16x8*)(Wb + (size_t) 0 * INF + k0 + quad * 8);
                s16x8 bf1 = *(const s16x8*)(Wb + (size_t)16 * INF + k0 + quad * 8);
                s16x8 bf2 = *(const s16x8*)(Wb + (size_t)32 * INF + k0 + quad * 8);
                s16x8 bf3 = *(const s16x8*)(Wb + (size_t)48 * INF + k0 + quad * 8);
                acc[0] = __builtin_amdgcn_mfma_f32_16x16x32_bf16(af, bf0, acc[0], 0, 0, 0);
                acc[1] = __builtin_amdgcn_mfma_f32_16x16x32_bf16(af, bf1, acc[1], 0, 0, 0);
                acc[2] = __builtin_amdgcn_mfma_f32_16x16x32_bf16(af, bf2, acc[2], 0, 0, 0);
                acc[3] = __builtin_amdgcn_mfma_f32_16x16x32_bf16(af, bf3, acc[3], 0, 0, 0);
            }
        }
    };

    // ---- phase 2: chunked FBS | GEMM1, double-buffered
    fbs_chunk(0, 0);
    __syncthreads();
    #pragma unroll
    for (int ch = 0; ch < NCHK; ++ch) {
        if (ch + 1 < NCHK) fbs_chunk(ch + 1, (ch + 1) & 1);
        mfma_chunk(ch, ch & 1);
        __syncthreads();                 // A[buf] consumed; next chunk may overwrite
    }

    // ---- phase 3: GEMM1 epilogue -> H1 (LDS; A space is now free)
    #pragma unroll
    for (int j = 0; j < 4; ++j) {
        int col = wn + j * 16 + lm;
        float bb = b1[col];
        #pragma unroll
        for (int rr = 0; rr < 4; ++rr) {
            int row = quad * 4 + rr;
            Hbase[row * 264 + col] = f2bf(fmaxf(acc[j][rr] + bb, 0.f));
        }
    }
    // r/d reduction (overlaps H1 writes; barrier below covers both)
    #pragma unroll
    for (int off = 32; off > 0; off >>= 1) {
        r += __shfl_down(r, off);
        d += __shfl_down(d, off);
    }
    if (lane == 0) { sr[wave] = r; sd[wave] = d; }
    __syncthreads();
    if (tid == 0) {
        int bk = blockIdx.x & 31;
        atomicAdd(&redcur[bk],      sr[0] + sr[1] + sr[2] + sr[3]);
        atomicAdd(&redcur[32 + bk], sd[0] + sd[1] + sd[2] + sd[3]);
    }

    // ---- phase 4: GEMM2 16x256, K=256 -> H2 (LDS)
    f32x4 a2[4];
    #pragma unroll
    for (int j = 0; j < 4; ++j) a2[j] = (f32x4){0.f, 0.f, 0.f, 0.f};
    {
        const ushort* W2b = Wt2 + (size_t)(wn + lm) * HID;
        #pragma unroll
        for (int k0 = 0; k0 < HID; k0 += 32) {
            s16x8 af = *(const s16x8*)&Hbase[lm * 264 + k0 + quad * 8];
            #pragma unroll
            for (int j = 0; j < 4; ++j) {
                s16x8 bf = *(const s16x8*)(W2b + (size_t)j * 16 * HID + k0 + quad * 8);
                a2[j] = __builtin_amdgcn_mfma_f32_16x16x32_bf16(af, bf, a2[j], 0, 0, 0);
            }
        }
    }
    #pragma unroll
    for (int j = 0; j < 4; ++j) {
        int col = wn + j * 16 + lm;
        float bb = b2[col];
        #pragma unroll
        for (int rr = 0; rr < 4; ++rr) {
            int row = quad * 4 + rr;
            Hbase[(16 + row) * 264 + col] = f2bf(fmaxf(a2[j][rr] + bb, 0.f));
        }
    }
    __syncthreads();                     // H2 complete (cross-wave)

    // ---- phase 5: GEMM3 16x1152, K=256; 3 passes of 96 cols/wave -> uv + Q
    float q = 0.f;
    #pragma unroll
    for (int pp = 0; pp < 3; ++pp) {
        f32x4 a3[6];
        #pragma unroll
        for (int j = 0; j < 6; ++j) a3[j] = (f32x4){0.f, 0.f, 0.f, 0.f};
        const int cb = pp * 384 + wave * 96;
        const ushort* W3b = Wt3 + (size_t)(cb + lm) * HID;
        #pragma unroll
        for (int k0 = 0; k0 < HID; k0 += 32) {
            s16x8 af = *(const s16x8*)&Hbase[(16 + lm) * 264 + k0 + quad * 8];
            #pragma unroll
            for (int j = 0; j < 6; ++j) {
                s16x8 bf = *(const s16x8*)(W3b + (size_t)j * 16 * HID + k0 + quad * 8);
                a3[j] = __builtin_amdgcn_mfma_f32_16x16x32_bf16(af, bf, a3[j], 0, 0, 0);
            }
        }
        #pragma unroll
        for (int j = 0; j < 6; ++j) {
            int col = cb + j * 16 + lm;
            float bb = b3[col];
            #pragma unroll
            for (int rr = 0; rr < 4; ++rr) {
                int row = quad * 4 + rr;
                float c = a3[j][rr] + bb;
                q += c * c;
                uv[(size_t)(m0 + row) * OUTF + col] = f2bf(c);
            }
        }
    }
    #pragma unroll
    for (int off = 32; off > 0; off >>= 1) q += __shfl_down(q, off);
    if (lane == 0) sq[wave] = q;
    __syncthreads();
    if (tid == 0)
        atomicAdd(&redcur[64 + (blockIdx.x & 31)], sq[0] + sq[1] + sq[2] + sq[3]);
}

// ---------- finish: p_final = S chunk 1; block 0 folds residuals -------------
__global__ __launch_bounds__(256) void k_finish(const float4* __restrict__ S4,
                                                float4* __restrict__ out4,
                                                const float* __restrict__ red,
                                                float* __restrict__ res_out,
                                                int total4) {
    int i = blockIdx.x * 256 + threadIdx.x;
    if (blockIdx.x == 0 && threadIdx.x < TS) {
        const float* rb = red + (threadIdx.x + 1) * 96;
        float s = 0.f;
        #pragma unroll
        for (int c = 0; c < 32; ++c) s += rb[c];
        res_out[threadIdx.x] = sqrtf(s + 1e-12f);
    }
    if (i >= total4) return;
    int sample = i / 144;
    int j = i - sample * 144;
    out4[i] = S4[(size_t)sample * 576 + 144 + j];
}

extern "C" void kernel_launch(void* const* d_in, const int* in_sizes, int n_in,
                              void* d_out, int out_size, void* d_ws, size_t ws_size,
                              hipStream_t stream) {
    const float* noisy = (const float*)d_in[0];
    const float* W1 = (const float*)d_in[1];
    const float* b1 = (const float*)d_in[2];
    const float* W2 = (const float*)d_in[3];
    const float* b2 = (const float*)d_in[4];
    const float* W3 = (const float*)d_in[5];
    const float* b3 = (const float*)d_in[6];
    const int B = in_sizes[0] / 64;   // 16384

    // workspace layout (~191 MB)
    float*  S   = (float*)d_ws;                         // [B,2304] f32
    ushort* uv  = (ushort*)(S + (size_t)B * INF);       // [B,1152] bf16
    ushort* Wt1 = uv + (size_t)B * OUTF;                // [256,2304] bf16
    ushort* Wt2 = Wt1 + (size_t)HID * INF;              // [256,256]  bf16
    ushort* Wt3 = Wt2 + (size_t)HID * HID;              // [1152,256] bf16
    float*  red = (float*)(Wt3 + (size_t)OUTF * HID);   // 21 slots x 96

    float* p_out   = (float*)d_out;                     // [B,576]
    float* res_out = p_out + (size_t)B * SVEC;          // [20]

    const int tot4 = B * 144;

    k_init<<<(tot4 * 4 + 255) / 256, 256, 0, stream>>>((float4*)S, (const float4*)noisy, tot4 * 4);
    k_zero<<<(21 * 96 + 127) / 128, 128, 0, stream>>>(red, 21 * 96);
    k_zero<<<((B * OUTF / 2) + 127) / 128, 128, 0, stream>>>((float*)uv, B * OUTF / 2);
    k_wt<<<(HID * INF + 255) / 256, 256, 0, stream>>>(W1, Wt1, INF, HID, HID * INF);
    k_wt<<<(HID * HID + 255) / 256, 256, 0, stream>>>(W2, Wt2, HID, HID, HID * HID);
    k_wt<<<(OUTF * HID + 255) / 256, 256, 0, stream>>>(W3, Wt3, HID, OUTF, OUTF * HID);

    const int gf = B / MR;      // 1024 blocks

    for (int n = 0; n < TS; ++n) {
        float an = (float)n / ((float)n + 3.0f);
        float* redprev = red + (size_t)n * 96;
        float* redcur  = red + (size_t)(n + 1) * 96;
        k_step<<<gf, 256, 0, stream>>>((float4*)S, uv, redprev, redcur,
                                       Wt1, b1, Wt2, b2, Wt3, b3, an);
    }
    k_finish<<<(tot4 + 255) / 256, 256, 0, stream>>>((const float4*)S, (float4*)p_out,
                                                     red, res_out, tot4);
}

// Round 8
// 3815.350 us; speedup vs baseline: 1.2331x; 1.2331x over previous
//
#include <hip/hip_runtime.h>
#include <math.h>

constexpr int SVEC = 576;    // N_CH * 64
constexpr int INF  = 2304;   // 4 * SVEC
constexpr int HID  = 256;
constexpr int OUTF = 1152;   // 2 * SVEC
constexpr int TS   = 20;
constexpr int RSL  = 104;    // red slot stride: rbuck[0:32] dbuck[32:64] qbuck[64:96] alpha[96]

// ---------- helpers ----------------------------------------------------------
__device__ __forceinline__ ushort f2bf(float f) {    // RNE f32->bf16
    union { float f; unsigned u; } a; a.f = f;
    unsigned r = a.u + 0x7fff + ((a.u >> 16) & 1);
    return (ushort)(r >> 16);
}
__device__ __forceinline__ float bf2f(ushort b) {
    union { unsigned u; float f; } a; a.u = ((unsigned)b) << 16;
    return a.f;
}

__device__ __forceinline__ void gload_lds16(const void* g, void* l) {
    __builtin_amdgcn_global_load_lds(
        (const __attribute__((address_space(1))) void*)g,
        (__attribute__((address_space(3))) void*)l, 16, 0, 0);
}

typedef short  s16x8 __attribute__((ext_vector_type(8)));
typedef float  f32x4 __attribute__((ext_vector_type(4)));

// ---------- init: S = [x|p|y|z] all = [noisy, 0...] --------------------------
__global__ __launch_bounds__(256) void k_init(float4* __restrict__ S4,
                                              const float4* __restrict__ noisy4,
                                              int total4) {
    int i = blockIdx.x * 256 + threadIdx.x;
    if (i >= total4) return;
    int sample = i / 576;
    int j = i - sample * 576;
    int jc = j % 144;
    float4 v = make_float4(0.f, 0.f, 0.f, 0.f);
    if (jc < 16) v = noisy4[sample * 16 + jc];
    S4[i] = v;
}

__global__ __launch_bounds__(128) void k_zero(float* __restrict__ p, int n) {
    int i = blockIdx.x * 128 + threadIdx.x;
    if (i < n) p[i] = 0.f;
}

// ---------- weight transpose + bf16 convert: Wt[n*K+k] = W[k*N+n] ------------
__global__ __launch_bounds__(256) void k_wt(const float* __restrict__ W,
                                            ushort* __restrict__ Wt,
                                            int K, int N, int total) {
    int i = blockIdx.x * 256 + threadIdx.x;
    if (i >= total) return;
    int n = i / K, k = i - n * K;
    Wt[i] = f2bf(W[(size_t)k * N + n]);
}

// ---------- per-step alpha: fold prev slot's d/Q buckets -> slot[96] ---------
__global__ void k_alpha(float* __restrict__ redprev) {
    int t = threadIdx.x;   // 64
    float v = (t < 32) ? redprev[32 + t] : redprev[64 + (t - 32)];
    #pragma unroll
    for (int off = 16; off > 0; off >>= 1) v += __shfl_down(v, off);
    float Q = __shfl(v, 32);   // qbuck sum
    if (t == 0) {
        float Qs = 1.5f * Q + 1e-12f;
        float b  = 0.99f * fmaxf(v, 0.f);   // v = dbuck sum
        redprev[96] = sqrtf(fminf(b / Qs, 1.f));
    }
}

// ---------- elementwise FBS (in-place on S); 2 float4-slots per thread -------
// No barriers; alpha via uniform s_load; 12 independent loads in flight.
__global__ __launch_bounds__(256) void k_fbs(float4* __restrict__ S4,
                                             const ushort4* __restrict__ uvb,
                                             const float* __restrict__ alpha_p,
                                             float* __restrict__ redcur,
                                             float an, int totPairs /* B*72 */) {
    int i = blockIdx.x * 256 + threadIdx.x;
    float r = 0.f, d = 0.f;
    if (i < totPairs) {
        int sample = i / 72;
        int jp = (i - sample * 72) * 2;          // float4 slots jp, jp+1
        size_t base = (size_t)sample * 576 + jp;
        size_t ub   = (size_t)sample * 288 + jp;
        const float al = *alpha_p;               // uniform scalar load
        // all 12 vector loads issued before any use
        float4 x0 = S4[base],       x1 = S4[base + 1];
        float4 p0 = S4[base + 144], p1 = S4[base + 145];
        float4 y0 = S4[base + 288], y1 = S4[base + 289];
        float4 z0 = S4[base + 432], z1 = S4[base + 433];
        ushort4 u0 = uvb[ub],       u1 = uvb[ub + 1];
        ushort4 v0 = uvb[ub + 144], v1 = uvb[ub + 145];
        float4 xo[2], po[2], yo[2], zo[2];
        const float4* XI[2] = {&x0, &x1}; const float4* PI[2] = {&p0, &p1};
        const float4* YI[2] = {&y0, &y1}; const float4* ZI[2] = {&z0, &z1};
        const ushort4* UI[2] = {&u0, &u1}; const ushort4* VI[2] = {&v0, &v1};
        #pragma unroll
        for (int g = 0; g < 2; ++g) {
            const float* X = (const float*)XI[g];  const float* P = (const float*)PI[g];
            const float* Y0 = (const float*)YI[g]; const float* Z0 = (const float*)ZI[g];
            const ushort* UB = (const ushort*)UI[g]; const ushort* VB = (const ushort*)VI[g];
            float* XN = (float*)&xo[g]; float* PR = (float*)&po[g];
            float* YY = (float*)&yo[g]; float* ZZ = (float*)&zo[g];
            #pragma unroll
            for (int c = 0; c < 4; ++c) {
                float x = X[c], p = P[c], yv = Y0[c], zv = Z0[c];
                float u = al * bf2f(UB[c]), v = al * bf2f(VB[c]);
                float y  = x + an * (yv - x) + u;
                float dz = an * (zv - p);
                float z  = x + an * (p - x) + dz + u + v;
                float zm = z - y;
                float t  = fabsf(zm) - 0.1f;
                float pr = (t > 0.f) ? copysignf(t, zm) : 0.f;
                float xn = x + (pr - z) + dz;
                XN[c] = xn; PR[c] = pr; YY[c] = y; ZZ[c] = z;
                float e1 = pr - y; r += e1 * e1;
                float e2 = xn - z; d += e2 * e2;
            }
        }
        S4[base]       = xo[0]; S4[base + 1]   = xo[1];
        S4[base + 144] = po[0]; S4[base + 145] = po[1];
        S4[base + 288] = yo[0]; S4[base + 289] = yo[1];
        S4[base + 432] = zo[0]; S4[base + 433] = zo[1];
    }
    #pragma unroll
    for (int off = 32; off > 0; off >>= 1) {
        r += __shfl_down(r, off);
        d += __shfl_down(d, off);
    }
    __shared__ float sr[4], sd[4];
    int lane = threadIdx.x & 63, wid = threadIdx.x >> 6;
    if (lane == 0) { sr[wid] = r; sd[wid] = d; }
    __syncthreads();
    if (threadIdx.x == 0) {
        int bk = blockIdx.x & 31;
        atomicAdd(&redcur[bk],      sr[0] + sr[1] + sr[2] + sr[3]);
        atomicAdd(&redcur[32 + bk], sd[0] + sd[1] + sd[2] + sd[3]);
    }
}

// ---------- bf16 MFMA GEMM: C[M,N] = A[M,K] @ Wt[N,K]^T + bias ---------------
// 256 thr = 4 waves (1 M x 4 N), tile 32x128, BK=32, 16x16x32 bf16 MFMA.
// AF32: A is f32, converted to bf16 during LDS staging (VGPR path).
template <bool AF32, bool RELU, bool QACC, bool BF16OUT, int NB>
__global__ __launch_bounds__(256) void k_gemm(const void* __restrict__ Avoid,
                                              const ushort* __restrict__ Wt,
                                              const float* __restrict__ bias,
                                              void* __restrict__ Cout,
                                              int K, int N,
                                              float* __restrict__ qbuck) {
    __shared__ ushort As[32 * 32];
    __shared__ ushort Bs[128 * 32];
    const int tid = threadIdx.x;
    const int bx = blockIdx.x;
    const int m0 = (bx / NB) * 32;
    const int n0 = (bx % NB) * 128;
    const int wave = tid >> 6, lane = tid & 63;
    const int wn = wave * 32;
    const int lm = lane & 15, quad = lane >> 4;

    f32x4 acc[2][2];
    #pragma unroll
    for (int i = 0; i < 2; ++i)
        #pragma unroll
        for (int j = 0; j < 2; ++j) acc[i][j] = (f32x4){0.f, 0.f, 0.f, 0.f};

    for (int k0 = 0; k0 < K; k0 += 32) {
        if (AF32) {
            const float* A = (const float*)Avoid;
            int rr = tid >> 3, kq = (tid & 7) << 2;
            float4 av = *(const float4*)(A + (size_t)(m0 + rr) * K + k0 + kq);
            ushort4 b4;
            b4.x = f2bf(av.x); b4.y = f2bf(av.y); b4.z = f2bf(av.z); b4.w = f2bf(av.w);
            *(ushort4*)&As[rr * 32 + kq] = b4;
        } else {
            const ushort* A = (const ushort*)Avoid;
            if (tid < 128) {
                int rr = tid >> 2, kq = (tid & 3) << 3;
                gload_lds16(A + (size_t)(m0 + rr) * K + k0 + kq, &As[tid * 8]);
            }
        }
        #pragma unroll
        for (int c = tid; c < 512; c += 256) {
            int rr = c >> 2, kq = (c & 3) << 3;
            gload_lds16(Wt + (size_t)(n0 + rr) * K + k0 + kq, &Bs[c * 8]);
        }
        __syncthreads();
        s16x8 af[2], bfr[2];
        #pragma unroll
        for (int i = 0; i < 2; ++i)
            af[i] = *(const s16x8*)&As[(i * 16 + lm) * 32 + quad * 8];
        #pragma unroll
        for (int j = 0; j < 2; ++j)
            bfr[j] = *(const s16x8*)&Bs[(wn + j * 16 + lm) * 32 + quad * 8];
        #pragma unroll
        for (int i = 0; i < 2; ++i)
            #pragma unroll
            for (int j = 0; j < 2; ++j)
                acc[i][j] = __builtin_amdgcn_mfma_f32_16x16x32_bf16(af[i], bfr[j], acc[i][j], 0, 0, 0);
        __syncthreads();
    }

    float q = 0.f;
    #pragma unroll
    for (int j = 0; j < 2; ++j) {
        int col = n0 + wn + j * 16 + lm;
        float bb = bias[col];
        #pragma unroll
        for (int i = 0; i < 2; ++i) {
            #pragma unroll
            for (int rr = 0; rr < 4; ++rr) {
                int row = m0 + i * 16 + quad * 4 + rr;
                float c = acc[i][j][rr] + bb;
                if (RELU) c = fmaxf(c, 0.f);
                if (QACC) q += c * c;
                if (BF16OUT) ((ushort*)Cout)[(size_t)row * N + col] = f2bf(c);
                else         ((float*)Cout)[(size_t)row * N + col] = c;
            }
        }
    }
    if (QACC) {
        #pragma unroll
        for (int off = 32; off > 0; off >>= 1) q += __shfl_down(q, off);
        __shared__ float sq[4];
        if (lane == 0) sq[wave] = q;
        __syncthreads();
        if (tid == 0) atomicAdd(&qbuck[bx & 31], sq[0] + sq[1] + sq[2] + sq[3]);
    }
}

// ---------- finish: p_final = S chunk 1; block 0 folds residuals -------------
__global__ __launch_bounds__(256) void k_finish(const float4* __restrict__ S4,
                                                float4* __restrict__ out4,
                                                const float* __restrict__ red,
                                                float* __restrict__ res_out,
                                                int total4) {
    int i = blockIdx.x * 256 + threadIdx.x;
    if (blockIdx.x == 0 && threadIdx.x < TS) {
        const float* rb = red + (size_t)(threadIdx.x + 1) * RSL;
        float s = 0.f;
        #pragma unroll
        for (int c = 0; c < 32; ++c) s += rb[c];
        res_out[threadIdx.x] = sqrtf(s + 1e-12f);
    }
    if (i >= total4) return;
    int sample = i / 144;
    int j = i - sample * 144;
    out4[i] = S4[(size_t)sample * 576 + 144 + j];
}

extern "C" void kernel_launch(void* const* d_in, const int* in_sizes, int n_in,
                              void* d_out, int out_size, void* d_ws, size_t ws_size,
                              hipStream_t stream) {
    const float* noisy = (const float*)d_in[0];
    const float* W1 = (const float*)d_in[1];
    const float* b1 = (const float*)d_in[2];
    const float* W2 = (const float*)d_in[3];
    const float* b2 = (const float*)d_in[4];
    const float* W3 = (const float*)d_in[5];
    const float* b3 = (const float*)d_in[6];
    const int B = in_sizes[0] / 64;   // 16384

    // workspace layout (~192 MB)
    float*  S   = (float*)d_ws;                         // [B,2304] f32
    ushort* uv  = (ushort*)(S + (size_t)B * INF);       // [B,1152] bf16
    ushort* h1  = uv + (size_t)B * OUTF;                // [B,256]  bf16
    ushort* h2  = h1 + (size_t)B * HID;                 // [B,256]  bf16
    ushort* Wt1 = h2 + (size_t)B * HID;                 // [256,2304] bf16
    ushort* Wt2 = Wt1 + (size_t)HID * INF;              // [256,256]  bf16
    ushort* Wt3 = Wt2 + (size_t)HID * HID;              // [1152,256] bf16
    float*  red = (float*)(Wt3 + (size_t)OUTF * HID);   // 21 slots x RSL

    float* p_out   = (float*)d_out;                     // [B,576]
    float* res_out = p_out + (size_t)B * SVEC;          // [20]

    const int tot4 = B * 144;
    const int totPairs = B * 72;

    k_init<<<(tot4 * 4 + 255) / 256, 256, 0, stream>>>((float4*)S, (const float4*)noisy, tot4 * 4);
    k_zero<<<(21 * RSL + 127) / 128, 128, 0, stream>>>(red, 21 * RSL);
    k_zero<<<((B * OUTF / 2) + 127) / 128, 128, 0, stream>>>((float*)uv, B * OUTF / 2);
    k_wt<<<(HID * INF + 255) / 256, 256, 0, stream>>>(W1, Wt1, INF, HID, HID * INF);
    k_wt<<<(HID * HID + 255) / 256, 256, 0, stream>>>(W2, Wt2, HID, HID, HID * HID);
    k_wt<<<(OUTF * HID + 255) / 256, 256, 0, stream>>>(W3, Wt3, HID, OUTF, OUTF * HID);

    const int gfb = (totPairs + 255) / 256;  // 4608 blocks
    const int g1  = (B / 32) * 2;            // 1024 blocks (NB=2)
    const int g2  = (B / 32) * 2;            // 1024 blocks (NB=2)
    const int g3  = (B / 32) * 9;            // 4608 blocks (NB=9)

    for (int n = 0; n < TS; ++n) {
        float an = (float)n / ((float)n + 3.0f);
        float* redprev = red + (size_t)n * RSL;
        float* redcur  = red + (size_t)(n + 1) * RSL;
        k_alpha<<<1, 64, 0, stream>>>(redprev);
        k_fbs<<<gfb, 256, 0, stream>>>((float4*)S, (const ushort4*)uv,
                                       redprev + 96, redcur, an, totPairs);
        k_gemm<true,  true,  false, true, 2><<<g1, 256, 0, stream>>>(S,  Wt1, b1, h1, INF, HID, nullptr);
        k_gemm<false, true,  false, true, 2><<<g2, 256, 0, stream>>>(h1, Wt2, b2, h2, HID, HID, nullptr);
        k_gemm<false, false, true,  true, 9><<<g3, 256, 0, stream>>>(h2, Wt3, b3, uv, HID, OUTF, redcur + 64);
    }
    k_finish<<<(tot4 + 255) / 256, 256, 0, stream>>>((const float4*)S, (float4*)p_out,
                                                     red, res_out, tot4);
}

// Round 9
// 3067.931 us; speedup vs baseline: 1.5335x; 1.2436x over previous
//
#include <hip/hip_runtime.h>
#include <math.h>

constexpr int SVEC = 576;    // N_CH * 64
constexpr int INF  = 2304;   // 4 * SVEC
constexpr int HID  = 256;
constexpr int OUTF = 1152;   // 2 * SVEC
constexpr int TS   = 20;
constexpr int RSL  = 104;    // red slot stride: rbuck[0:32] dbuck[32:64] qbuck[64:96] alpha[96]

// ---------- helpers ----------------------------------------------------------
__device__ __forceinline__ ushort f2bf(float f) {    // RNE f32->bf16
    union { float f; unsigned u; } a; a.f = f;
    unsigned r = a.u + 0x7fff + ((a.u >> 16) & 1);
    return (ushort)(r >> 16);
}
__device__ __forceinline__ float bf2f(ushort b) {
    union { unsigned u; float f; } a; a.u = ((unsigned)b) << 16;
    return a.f;
}

__device__ __forceinline__ void gload_lds16(const void* g, void* l) {
    __builtin_amdgcn_global_load_lds(
        (const __attribute__((address_space(1))) void*)g,
        (__attribute__((address_space(3))) void*)l, 16, 0, 0);
}

typedef short  s16x8 __attribute__((ext_vector_type(8)));
typedef float  f32x4 __attribute__((ext_vector_type(4)));

// ---------- init: Sb(bf16) = [x|p|y|z] all = [noisy, 0...] -------------------
// one thread per s16x8 slot (8 elems); B*288 slots
__global__ __launch_bounds__(256) void k_init(ushort* __restrict__ Sb,
                                              const float4* __restrict__ noisy4,
                                              int tot8) {
    int i = blockIdx.x * 256 + threadIdx.x;
    if (i >= tot8) return;
    int sample = i / 288;
    int j = i - sample * 288;       // slot within sample
    int jc = j % 72;                // slot within chunk
    s16x8 o = (s16x8){0,0,0,0,0,0,0,0};
    if (jc < 8) {                   // first 64 elems = noisy
        float4 a = noisy4[sample * 16 + jc * 2];
        float4 b = noisy4[sample * 16 + jc * 2 + 1];
        ushort* u = (ushort*)&o;
        u[0]=f2bf(a.x); u[1]=f2bf(a.y); u[2]=f2bf(a.z); u[3]=f2bf(a.w);
        u[4]=f2bf(b.x); u[5]=f2bf(b.y); u[6]=f2bf(b.z); u[7]=f2bf(b.w);
    }
    *(s16x8*)&Sb[(size_t)i * 8] = o;
}

__global__ __launch_bounds__(128) void k_zero(float* __restrict__ p, int n) {
    int i = blockIdx.x * 128 + threadIdx.x;
    if (i < n) p[i] = 0.f;
}

// ---------- weight transpose + bf16 convert: Wt[n*K+k] = W[k*N+n] ------------
__global__ __launch_bounds__(256) void k_wt(const float* __restrict__ W,
                                            ushort* __restrict__ Wt,
                                            int K, int N, int total) {
    int i = blockIdx.x * 256 + threadIdx.x;
    if (i >= total) return;
    int n = i / K, k = i - n * K;
    Wt[i] = f2bf(W[(size_t)k * N + n]);
}

// ---------- per-step alpha: fold prev slot's d/Q buckets -> slot[96] ---------
__global__ void k_alpha(float* __restrict__ redprev) {
    int t = threadIdx.x;   // 64
    float v = (t < 32) ? redprev[32 + t] : redprev[64 + (t - 32)];
    #pragma unroll
    for (int off = 16; off > 0; off >>= 1) v += __shfl_down(v, off);
    float Q = __shfl(v, 32);   // qbuck sum
    if (t == 0) {
        float Qs = 1.5f * Q + 1e-12f;
        float b  = 0.99f * fmaxf(v, 0.f);   // v = dbuck sum
        redprev[96] = sqrtf(fminf(b / Qs, 1.f));
    }
}

// ---------- elementwise FBS (in-place on bf16 Sb); 8 elems per thread --------
// No barriers before compute; alpha via uniform scalar load; f32 math.
__global__ __launch_bounds__(256) void k_fbs(ushort* __restrict__ Sb,
                                             const ushort* __restrict__ uv,
                                             const float* __restrict__ alpha_p,
                                             float* __restrict__ redcur,
                                             float an, int tot8 /* B*72 */) {
    int i = blockIdx.x * 256 + threadIdx.x;
    float r = 0.f, d = 0.f;
    if (i < tot8) {
        int sample = i / 72;
        int j8 = i - sample * 72;
        size_t sb = (size_t)sample * INF + j8 * 8;
        size_t ub = (size_t)sample * OUTF + j8 * 8;
        const float al = *alpha_p;
        s16x8 x8 = *(const s16x8*)(Sb + sb);
        s16x8 p8 = *(const s16x8*)(Sb + sb + 576);
        s16x8 y8 = *(const s16x8*)(Sb + sb + 1152);
        s16x8 z8 = *(const s16x8*)(Sb + sb + 1728);
        s16x8 u8 = *(const s16x8*)(uv + ub);
        s16x8 v8 = *(const s16x8*)(uv + ub + 576);
        s16x8 xo, po, yo, zo;
        const ushort* X = (const ushort*)&x8; const ushort* P = (const ushort*)&p8;
        const ushort* Y = (const ushort*)&y8; const ushort* Z = (const ushort*)&z8;
        const ushort* U = (const ushort*)&u8; const ushort* V = (const ushort*)&v8;
        ushort* XO = (ushort*)&xo; ushort* PO = (ushort*)&po;
        ushort* YO = (ushort*)&yo; ushort* ZO = (ushort*)&zo;
        #pragma unroll
        for (int c = 0; c < 8; ++c) {
            float x = bf2f(X[c]), p = bf2f(P[c]);
            float yv = bf2f(Y[c]), zv = bf2f(Z[c]);
            float u = al * bf2f(U[c]), v = al * bf2f(V[c]);
            float y  = x + an * (yv - x) + u;
            float dz = an * (zv - p);
            float z  = x + an * (p - x) + dz + u + v;
            float zm = z - y;
            float t  = fabsf(zm) - 0.1f;
            float pr = (t > 0.f) ? copysignf(t, zm) : 0.f;
            float xn = x + (pr - z) + dz;
            XO[c] = f2bf(xn); PO[c] = f2bf(pr); YO[c] = f2bf(y); ZO[c] = f2bf(z);
            float e1 = pr - y; r += e1 * e1;
            float e2 = xn - z; d += e2 * e2;
        }
        *(s16x8*)(Sb + sb)        = xo;
        *(s16x8*)(Sb + sb + 576)  = po;
        *(s16x8*)(Sb + sb + 1152) = yo;
        *(s16x8*)(Sb + sb + 1728) = zo;
    }
    #pragma unroll
    for (int off = 32; off > 0; off >>= 1) {
        r += __shfl_down(r, off);
        d += __shfl_down(d, off);
    }
    __shared__ float sr[4], sd[4];
    int lane = threadIdx.x & 63, wid = threadIdx.x >> 6;
    if (lane == 0) { sr[wid] = r; sd[wid] = d; }
    __syncthreads();
    if (threadIdx.x == 0) {
        int bk = blockIdx.x & 31;
        atomicAdd(&redcur[bk],      sr[0] + sr[1] + sr[2] + sr[3]);
        atomicAdd(&redcur[32 + bk], sd[0] + sd[1] + sd[2] + sd[3]);
    }
}

// ---------- bf16 MFMA GEMM: C[M,N] = A[M,K] @ Wt[N,K]^T + bias ---------------
// 256 thr = 4 waves (1 M x 4 N), tile 32x128, BK=32, 16x16x32 bf16 MFMA.
template <bool RELU, bool QACC, bool BF16OUT, int NB>
__global__ __launch_bounds__(256) void k_gemm(const ushort* __restrict__ A,
                                              const ushort* __restrict__ Wt,
                                              const float* __restrict__ bias,
                                              void* __restrict__ Cout,
                                              int K, int N,
                                              float* __restrict__ qbuck) {
    __shared__ ushort As[32 * 32];
    __shared__ ushort Bs[128 * 32];
    const int tid = threadIdx.x;
    const int bx = blockIdx.x;
    const int m0 = (bx / NB) * 32;
    const int n0 = (bx % NB) * 128;
    const int wave = tid >> 6, lane = tid & 63;
    const int wn = wave * 32;
    const int lm = lane & 15, quad = lane >> 4;

    f32x4 acc[2][2];
    #pragma unroll
    for (int i = 0; i < 2; ++i)
        #pragma unroll
        for (int j = 0; j < 2; ++j) acc[i][j] = (f32x4){0.f, 0.f, 0.f, 0.f};

    for (int k0 = 0; k0 < K; k0 += 32) {
        if (tid < 128) {                         // A: 32 rows x 4 chunks16
            int rr = tid >> 2, kq = (tid & 3) << 3;
            gload_lds16(A + (size_t)(m0 + rr) * K + k0 + kq, &As[tid * 8]);
        }
        #pragma unroll
        for (int c = tid; c < 512; c += 256) {   // B: 128 rows x 4 chunks16
            int rr = c >> 2, kq = (c & 3) << 3;
            gload_lds16(Wt + (size_t)(n0 + rr) * K + k0 + kq, &Bs[c * 8]);
        }
        __syncthreads();
        s16x8 af[2], bfr[2];
        #pragma unroll
        for (int i = 0; i < 2; ++i)
            af[i] = *(const s16x8*)&As[(i * 16 + lm) * 32 + quad * 8];
        #pragma unroll
        for (int j = 0; j < 2; ++j)
            bfr[j] = *(const s16x8*)&Bs[(wn + j * 16 + lm) * 32 + quad * 8];
        #pragma unroll
        for (int i = 0; i < 2; ++i)
            #pragma unroll
            for (int j = 0; j < 2; ++j)
                acc[i][j] = __builtin_amdgcn_mfma_f32_16x16x32_bf16(af[i], bfr[j], acc[i][j], 0, 0, 0);
        __syncthreads();
    }

    float q = 0.f;
    #pragma unroll
    for (int j = 0; j < 2; ++j) {
        int col = n0 + wn + j * 16 + lm;
        float bb = bias[col];
        #pragma unroll
        for (int i = 0; i < 2; ++i) {
            #pragma unroll
            for (int rr = 0; rr < 4; ++rr) {
                int row = m0 + i * 16 + quad * 4 + rr;
                float c = acc[i][j][rr] + bb;
                if (RELU) c = fmaxf(c, 0.f);
                if (QACC) q += c * c;
                if (BF16OUT) ((ushort*)Cout)[(size_t)row * N + col] = f2bf(c);
                else         ((float*)Cout)[(size_t)row * N + col] = c;
            }
        }
    }
    if (QACC) {
        #pragma unroll
        for (int off = 32; off > 0; off >>= 1) q += __shfl_down(q, off);
        __shared__ float sq[4];
        if (lane == 0) sq[wave] = q;
        __syncthreads();
        if (tid == 0) atomicAdd(&qbuck[bx & 31], sq[0] + sq[1] + sq[2] + sq[3]);
    }
}

// ---------- finish: p_final (bf16->f32) ; block 0 folds residuals ------------
__global__ __launch_bounds__(256) void k_finish(const ushort* __restrict__ Sb,
                                                float4* __restrict__ out4,
                                                const float* __restrict__ red,
                                                float* __restrict__ res_out,
                                                int total4 /* B*144 */) {
    int i = blockIdx.x * 256 + threadIdx.x;
    if (blockIdx.x == 0 && threadIdx.x < TS) {
        const float* rb = red + (size_t)(threadIdx.x + 1) * RSL;
        float s = 0.f;
        #pragma unroll
        for (int c = 0; c < 32; ++c) s += rb[c];
        res_out[threadIdx.x] = sqrtf(s + 1e-12f);
    }
    if (i >= total4) return;
    int sample = i / 144;
    int j = i - sample * 144;
    const ushort* p = Sb + (size_t)sample * INF + 576 + j * 4;
    float4 o;
    o.x = bf2f(p[0]); o.y = bf2f(p[1]); o.z = bf2f(p[2]); o.w = bf2f(p[3]);
    out4[i] = o;
}

extern "C" void kernel_launch(void* const* d_in, const int* in_sizes, int n_in,
                              void* d_out, int out_size, void* d_ws, size_t ws_size,
                              hipStream_t stream) {
    const float* noisy = (const float*)d_in[0];
    const float* W1 = (const float*)d_in[1];
    const float* b1 = (const float*)d_in[2];
    const float* W2 = (const float*)d_in[3];
    const float* b2 = (const float*)d_in[4];
    const float* W3 = (const float*)d_in[5];
    const float* b3 = (const float*)d_in[6];
    const int B = in_sizes[0] / 64;   // 16384

    // workspace layout (~132 MB)
    ushort* Sb  = (ushort*)d_ws;                        // [B,2304] bf16
    ushort* uv  = Sb + (size_t)B * INF;                 // [B,1152] bf16
    ushort* h1  = uv + (size_t)B * OUTF;                // [B,256]  bf16
    ushort* h2  = h1 + (size_t)B * HID;                 // [B,256]  bf16
    ushort* Wt1 = h2 + (size_t)B * HID;                 // [256,2304] bf16
    ushort* Wt2 = Wt1 + (size_t)HID * INF;              // [256,256]  bf16
    ushort* Wt3 = Wt2 + (size_t)HID * HID;              // [1152,256] bf16
    float*  red = (float*)(Wt3 + (size_t)OUTF * HID);   // 21 slots x RSL

    float* p_out   = (float*)d_out;                     // [B,576]
    float* res_out = p_out + (size_t)B * SVEC;          // [20]

    const int tot8S = B * 288;   // s16x8 slots in Sb
    const int tot8  = B * 72;    // s16x8 slots per chunk
    const int tot4  = B * 144;   // float4 units of output 0

    k_init<<<(tot8S + 255) / 256, 256, 0, stream>>>(Sb, (const float4*)noisy, tot8S);
    k_zero<<<(21 * RSL + 127) / 128, 128, 0, stream>>>(red, 21 * RSL);
    k_zero<<<((B * OUTF / 2) + 127) / 128, 128, 0, stream>>>((float*)uv, B * OUTF / 2);
    k_wt<<<(HID * INF + 255) / 256, 256, 0, stream>>>(W1, Wt1, INF, HID, HID * INF);
    k_wt<<<(HID * HID + 255) / 256, 256, 0, stream>>>(W2, Wt2, HID, HID, HID * HID);
    k_wt<<<(OUTF * HID + 255) / 256, 256, 0, stream>>>(W3, Wt3, HID, OUTF, OUTF * HID);

    const int gfb = (tot8 + 255) / 256;      // 4608 blocks
    const int g1  = (B / 32) * 2;            // 1024 blocks (NB=2)
    const int g2  = (B / 32) * 2;            // 1024 blocks (NB=2)
    const int g3  = (B / 32) * 9;            // 4608 blocks (NB=9)

    for (int n = 0; n < TS; ++n) {
        float an = (float)n / ((float)n + 3.0f);
        float* redprev = red + (size_t)n * RSL;
        float* redcur  = red + (size_t)(n + 1) * RSL;
        k_alpha<<<1, 64, 0, stream>>>(redprev);
        k_fbs<<<gfb, 256, 0, stream>>>(Sb, uv, redprev + 96, redcur, an, tot8);
        k_gemm<true,  false, true, 2><<<g1, 256, 0, stream>>>(Sb, Wt1, b1, h1, INF, HID, nullptr);
        k_gemm<true,  false, true, 2><<<g2, 256, 0, stream>>>(h1, Wt2, b2, h2, HID, HID, nullptr);
        k_gemm<false, true,  true, 9><<<g3, 256, 0, stream>>>(h2, Wt3, b3, uv, HID, OUTF, redcur + 64);
    }
    k_finish<<<(tot4 + 255) / 256, 256, 0, stream>>>(Sb, (float4*)p_out,
                                                     red, res_out, tot4);
}

// Round 10
// 2645.022 us; speedup vs baseline: 1.7787x; 1.1599x over previous
//
#include <hip/hip_runtime.h>
#include <math.h>

constexpr int SVEC = 576;    // N_CH * 64
constexpr int INF  = 2304;   // 4 * SVEC
constexpr int HID  = 256;
constexpr int OUTF = 1152;   // 2 * SVEC
constexpr int TS   = 20;
constexpr int RSL  = 104;    // red slot stride: rbuck[0:32] dbuck[32:64] qbuck[64:96] alpha[96]

// ---------- helpers ----------------------------------------------------------
__device__ __forceinline__ ushort f2bf(float f) {    // RNE f32->bf16
    union { float f; unsigned u; } a; a.f = f;
    unsigned r = a.u + 0x7fff + ((a.u >> 16) & 1);
    return (ushort)(r >> 16);
}
__device__ __forceinline__ float bf2f(ushort b) {
    union { unsigned u; float f; } a; a.u = ((unsigned)b) << 16;
    return a.f;
}

__device__ __forceinline__ void gload_lds16(const void* g, void* l) {
    __builtin_amdgcn_global_load_lds(
        (const __attribute__((address_space(1))) void*)g,
        (__attribute__((address_space(3))) void*)l, 16, 0, 0);
}

typedef short  s16x8 __attribute__((ext_vector_type(8)));
typedef float  f32x4 __attribute__((ext_vector_type(4)));

// ---------- init: Sb(bf16) = [x|p|y|z] all = [noisy, 0...] -------------------
__global__ __launch_bounds__(256) void k_init(ushort* __restrict__ Sb,
                                              const float4* __restrict__ noisy4,
                                              int tot8) {
    int i = blockIdx.x * 256 + threadIdx.x;
    if (i >= tot8) return;
    int sample = i / 288;
    int j = i - sample * 288;       // slot within sample
    int jc = j % 72;                // slot within chunk
    s16x8 o = (s16x8){0,0,0,0,0,0,0,0};
    if (jc < 8) {                   // first 64 elems = noisy
        float4 a = noisy4[sample * 16 + jc * 2];
        float4 b = noisy4[sample * 16 + jc * 2 + 1];
        ushort* u = (ushort*)&o;
        u[0]=f2bf(a.x); u[1]=f2bf(a.y); u[2]=f2bf(a.z); u[3]=f2bf(a.w);
        u[4]=f2bf(b.x); u[5]=f2bf(b.y); u[6]=f2bf(b.z); u[7]=f2bf(b.w);
    }
    *(s16x8*)&Sb[(size_t)i * 8] = o;
}

__global__ __launch_bounds__(128) void k_zero(float* __restrict__ p, int n) {
    int i = blockIdx.x * 128 + threadIdx.x;
    if (i < n) p[i] = 0.f;
}

// ---------- weight transpose + bf16 convert: Wt[n*K+k] = W[k*N+n] ------------
__global__ __launch_bounds__(256) void k_wt(const float* __restrict__ W,
                                            ushort* __restrict__ Wt,
                                            int K, int N, int total) {
    int i = blockIdx.x * 256 + threadIdx.x;
    if (i >= total) return;
    int n = i / K, k = i - n * K;
    Wt[i] = f2bf(W[(size_t)k * N + n]);
}

// ---------- per-step alpha: fold prev slot's d/Q buckets -> slot[96] ---------
__global__ void k_alpha(float* __restrict__ redprev) {
    int t = threadIdx.x;   // 64
    float v = (t < 32) ? redprev[32 + t] : redprev[64 + (t - 32)];
    #pragma unroll
    for (int off = 16; off > 0; off >>= 1) v += __shfl_down(v, off);
    float Q = __shfl(v, 32);   // qbuck sum
    if (t == 0) {
        float Qs = 1.5f * Q + 1e-12f;
        float b  = 0.99f * fmaxf(v, 0.f);   // v = dbuck sum
        redprev[96] = sqrtf(fminf(b / Qs, 1.f));
    }
}

// ---------- elementwise FBS (in-place on bf16 Sb); 16 elems per thread -------
// No barriers before compute; 12 independent 16B loads in flight.
__global__ __launch_bounds__(256) void k_fbs(ushort* __restrict__ Sb,
                                             const ushort* __restrict__ uv,
                                             const float* __restrict__ alpha_p,
                                             float* __restrict__ redcur,
                                             float an, int tot16 /* B*36 */) {
    int i = blockIdx.x * 256 + threadIdx.x;
    float r = 0.f, d = 0.f;
    if (i < tot16) {
        int sample = i / 36;
        int j16 = (i - sample * 36) * 16;        // elem offset within chunk
        size_t sb = (size_t)sample * INF + j16;
        size_t ub = (size_t)sample * OUTF + j16;
        const float al = *alpha_p;
        // 12 loads issued back-to-back
        s16x8 x8a = *(const s16x8*)(Sb + sb),        x8b = *(const s16x8*)(Sb + sb + 8);
        s16x8 p8a = *(const s16x8*)(Sb + sb + 576),  p8b = *(const s16x8*)(Sb + sb + 584);
        s16x8 y8a = *(const s16x8*)(Sb + sb + 1152), y8b = *(const s16x8*)(Sb + sb + 1160);
        s16x8 z8a = *(const s16x8*)(Sb + sb + 1728), z8b = *(const s16x8*)(Sb + sb + 1736);
        s16x8 u8a = *(const s16x8*)(uv + ub),        u8b = *(const s16x8*)(uv + ub + 8);
        s16x8 v8a = *(const s16x8*)(uv + ub + 576),  v8b = *(const s16x8*)(uv + ub + 584);
        s16x8 xo[2], po[2], yo[2], zo[2];
        const s16x8* XI[2] = {&x8a, &x8b}; const s16x8* PI[2] = {&p8a, &p8b};
        const s16x8* YI[2] = {&y8a, &y8b}; const s16x8* ZI[2] = {&z8a, &z8b};
        const s16x8* UI[2] = {&u8a, &u8b}; const s16x8* VI[2] = {&v8a, &v8b};
        #pragma unroll
        for (int g = 0; g < 2; ++g) {
            const ushort* X = (const ushort*)XI[g]; const ushort* P = (const ushort*)PI[g];
            const ushort* Y = (const ushort*)YI[g]; const ushort* Z = (const ushort*)ZI[g];
            const ushort* U = (const ushort*)UI[g]; const ushort* V = (const ushort*)VI[g];
            ushort* XO = (ushort*)&xo[g]; ushort* PO = (ushort*)&po[g];
            ushort* YO = (ushort*)&yo[g]; ushort* ZO = (ushort*)&zo[g];
            #pragma unroll
            for (int c = 0; c < 8; ++c) {
                float x = bf2f(X[c]), p = bf2f(P[c]);
                float yv = bf2f(Y[c]), zv = bf2f(Z[c]);
                float u = al * bf2f(U[c]), v = al * bf2f(V[c]);
                float y  = x + an * (yv - x) + u;
                float dz = an * (zv - p);
                float z  = x + an * (p - x) + dz + u + v;
                float zm = z - y;
                float t  = fabsf(zm) - 0.1f;
                float pr = (t > 0.f) ? copysignf(t, zm) : 0.f;
                float xn = x + (pr - z) + dz;
                XO[c] = f2bf(xn); PO[c] = f2bf(pr); YO[c] = f2bf(y); ZO[c] = f2bf(z);
                float e1 = pr - y; r += e1 * e1;
                float e2 = xn - z; d += e2 * e2;
            }
        }
        *(s16x8*)(Sb + sb)        = xo[0]; *(s16x8*)(Sb + sb + 8)    = xo[1];
        *(s16x8*)(Sb + sb + 576)  = po[0]; *(s16x8*)(Sb + sb + 584)  = po[1];
        *(s16x8*)(Sb + sb + 1152) = yo[0]; *(s16x8*)(Sb + sb + 1160) = yo[1];
        *(s16x8*)(Sb + sb + 1728) = zo[0]; *(s16x8*)(Sb + sb + 1736) = zo[1];
    }
    #pragma unroll
    for (int off = 32; off > 0; off >>= 1) {
        r += __shfl_down(r, off);
        d += __shfl_down(d, off);
    }
    __shared__ float sr[4], sd[4];
    int lane = threadIdx.x & 63, wid = threadIdx.x >> 6;
    if (lane == 0) { sr[wid] = r; sd[wid] = d; }
    __syncthreads();
    if (threadIdx.x == 0) {
        int bk = blockIdx.x & 31;
        atomicAdd(&redcur[bk],      sr[0] + sr[1] + sr[2] + sr[3]);
        atomicAdd(&redcur[32 + bk], sd[0] + sd[1] + sd[2] + sd[3]);
    }
}

// ---------- bf16 MFMA GEMM: C[M,N] = A[M,K] @ Wt[N,K]^T + bias ---------------
// 256 thr = 4 waves (1 M x 4 N), tile 32x128, BK templated, 16x16x32 MFMA.
template <int BK, bool RELU, bool QACC, bool BF16OUT, int NB>
__global__ __launch_bounds__(256) void k_gemm(const ushort* __restrict__ A,
                                              const ushort* __restrict__ Wt,
                                              const float* __restrict__ bias,
                                              void* __restrict__ Cout,
                                              int K, int N,
                                              float* __restrict__ qbuck) {
    __shared__ ushort As[32 * BK];
    __shared__ ushort Bs[128 * BK];
    const int tid = threadIdx.x;
    const int bx = blockIdx.x;
    const int m0 = (bx / NB) * 32;
    const int n0 = (bx % NB) * 128;
    const int wave = tid >> 6, lane = tid & 63;
    const int wn = wave * 32;
    const int lm = lane & 15, quad = lane >> 4;
    constexpr int CPB = BK / 8;              // 16B chunks per row

    f32x4 acc[2][2];
    #pragma unroll
    for (int i = 0; i < 2; ++i)
        #pragma unroll
        for (int j = 0; j < 2; ++j) acc[i][j] = (f32x4){0.f, 0.f, 0.f, 0.f};

    for (int k0 = 0; k0 < K; k0 += BK) {
        #pragma unroll
        for (int c = tid; c < 32 * CPB; c += 256) {      // A: 32 rows
            int rr = c / CPB, kq = (c % CPB) * 8;
            gload_lds16(A + (size_t)(m0 + rr) * K + k0 + kq, &As[c * 8]);
        }
        #pragma unroll
        for (int c = tid; c < 128 * CPB; c += 256) {     // B: 128 rows
            int rr = c / CPB, kq = (c % CPB) * 8;
            gload_lds16(Wt + (size_t)(n0 + rr) * K + k0 + kq, &Bs[c * 8]);
        }
        __syncthreads();
        #pragma unroll
        for (int kk = 0; kk < BK; kk += 32) {
            s16x8 af[2], bfr[2];
            #pragma unroll
            for (int i = 0; i < 2; ++i)
                af[i] = *(const s16x8*)&As[(i * 16 + lm) * BK + kk + quad * 8];
            #pragma unroll
            for (int j = 0; j < 2; ++j)
                bfr[j] = *(const s16x8*)&Bs[(wn + j * 16 + lm) * BK + kk + quad * 8];
            #pragma unroll
            for (int i = 0; i < 2; ++i)
                #pragma unroll
                for (int j = 0; j < 2; ++j)
                    acc[i][j] = __builtin_amdgcn_mfma_f32_16x16x32_bf16(af[i], bfr[j], acc[i][j], 0, 0, 0);
        }
        __syncthreads();
    }

    float q = 0.f;
    #pragma unroll
    for (int j = 0; j < 2; ++j) {
        int col = n0 + wn + j * 16 + lm;
        float bb = bias[col];
        #pragma unroll
        for (int i = 0; i < 2; ++i) {
            #pragma unroll
            for (int rr = 0; rr < 4; ++rr) {
                int row = m0 + i * 16 + quad * 4 + rr;
                float c = acc[i][j][rr] + bb;
                if (RELU) c = fmaxf(c, 0.f);
                if (QACC) q += c * c;
                if (BF16OUT) ((ushort*)Cout)[(size_t)row * N + col] = f2bf(c);
                else         ((float*)Cout)[(size_t)row * N + col] = c;
            }
        }
    }
    if (QACC) {
        #pragma unroll
        for (int off = 32; off > 0; off >>= 1) q += __shfl_down(q, off);
        __shared__ float sq[4];
        if (lane == 0) sq[wave] = q;
        __syncthreads();
        if (tid == 0) atomicAdd(&qbuck[bx & 31], sq[0] + sq[1] + sq[2] + sq[3]);
    }
}

// ---------- finish: p_final (bf16->f32) ; block 0 folds residuals ------------
__global__ __launch_bounds__(256) void k_finish(const ushort* __restrict__ Sb,
                                                float4* __restrict__ out4,
                                                const float* __restrict__ red,
                                                float* __restrict__ res_out,
                                                int total4 /* B*144 */) {
    int i = blockIdx.x * 256 + threadIdx.x;
    if (blockIdx.x == 0 && threadIdx.x < TS) {
        const float* rb = red + (size_t)(threadIdx.x + 1) * RSL;
        float s = 0.f;
        #pragma unroll
        for (int c = 0; c < 32; ++c) s += rb[c];
        res_out[threadIdx.x] = sqrtf(s + 1e-12f);
    }
    if (i >= total4) return;
    int sample = i / 144;
    int j = i - sample * 144;
    const ushort* p = Sb + (size_t)sample * INF + 576 + j * 4;
    float4 o;
    o.x = bf2f(p[0]); o.y = bf2f(p[1]); o.z = bf2f(p[2]); o.w = bf2f(p[3]);
    out4[i] = o;
}

extern "C" void kernel_launch(void* const* d_in, const int* in_sizes, int n_in,
                              void* d_out, int out_size, void* d_ws, size_t ws_size,
                              hipStream_t stream) {
    const float* noisy = (const float*)d_in[0];
    const float* W1 = (const float*)d_in[1];
    const float* b1 = (const float*)d_in[2];
    const float* W2 = (const float*)d_in[3];
    const float* b2 = (const float*)d_in[4];
    const float* W3 = (const float*)d_in[5];
    const float* b3 = (const float*)d_in[6];
    const int B = in_sizes[0] / 64;   // 16384

    // workspace layout (~132 MB)
    ushort* Sb  = (ushort*)d_ws;                        // [B,2304] bf16
    ushort* uv  = Sb + (size_t)B * INF;                 // [B,1152] bf16
    ushort* h1  = uv + (size_t)B * OUTF;                // [B,256]  bf16
    ushort* h2  = h1 + (size_t)B * HID;                 // [B,256]  bf16
    ushort* Wt1 = h2 + (size_t)B * HID;                 // [256,2304] bf16
    ushort* Wt2 = Wt1 + (size_t)HID * INF;              // [256,256]  bf16
    ushort* Wt3 = Wt2 + (size_t)HID * HID;              // [1152,256] bf16
    float*  red = (float*)(Wt3 + (size_t)OUTF * HID);   // 21 slots x RSL

    float* p_out   = (float*)d_out;                     // [B,576]
    float* res_out = p_out + (size_t)B * SVEC;          // [20]

    const int tot8S = B * 288;   // s16x8 slots in Sb
    const int tot16 = B * 36;    // 16-elem groups per chunk
    const int tot4  = B * 144;   // float4 units of output 0

    k_init<<<(tot8S + 255) / 256, 256, 0, stream>>>(Sb, (const float4*)noisy, tot8S);
    k_zero<<<(21 * RSL + 127) / 128, 128, 0, stream>>>(red, 21 * RSL);
    k_zero<<<((B * OUTF / 2) + 127) / 128, 128, 0, stream>>>((float*)uv, B * OUTF / 2);
    k_wt<<<(HID * INF + 255) / 256, 256, 0, stream>>>(W1, Wt1, INF, HID, HID * INF);
    k_wt<<<(HID * HID + 255) / 256, 256, 0, stream>>>(W2, Wt2, HID, HID, HID * HID);
    k_wt<<<(OUTF * HID + 255) / 256, 256, 0, stream>>>(W3, Wt3, HID, OUTF, OUTF * HID);

    const int gfb = (tot16 + 255) / 256;     // 2304 blocks
    const int g1  = (B / 32) * 2;            // 1024 blocks (NB=2)
    const int g2  = (B / 32) * 2;            // 1024 blocks (NB=2)
    const int g3  = (B / 32) * 9;            // 4608 blocks (NB=9)

    for (int n = 0; n < TS; ++n) {
        float an = (float)n / ((float)n + 3.0f);
        float* redprev = red + (size_t)n * RSL;
        float* redcur  = red + (size_t)(n + 1) * RSL;
        k_alpha<<<1, 64, 0, stream>>>(redprev);
        k_fbs<<<gfb, 256, 0, stream>>>(Sb, uv, redprev + 96, redcur, an, tot16);
        k_gemm<64, true,  false, true, 2><<<g1, 256, 0, stream>>>(Sb, Wt1, b1, h1, INF, HID, nullptr);
        k_gemm<64, true,  false, true, 2><<<g2, 256, 0, stream>>>(h1, Wt2, b2, h2, HID, HID, nullptr);
        k_gemm<32, false, true,  true, 9><<<g3, 256, 0, stream>>>(h2, Wt3, b3, uv, HID, OUTF, redcur + 64);
    }
    k_finish<<<(tot4 + 255) / 256, 256, 0, stream>>>(Sb, (float4*)p_out,
                                                     red, res_out, tot4);
}